// Round 12
// baseline (191.305 us; speedup 1.0000x reference)
//
#include <hip/hip_runtime.h>

#define DEVI __device__ __forceinline__

typedef float f32x4 __attribute__((ext_vector_type(4)));
typedef float f32x16 __attribute__((ext_vector_type(16)));
typedef short bf16x8 __attribute__((ext_vector_type(8)));
typedef unsigned int uint2v __attribute__((ext_vector_type(2)));

DEVI unsigned short f2bf(float f) {
  union { float f; unsigned int u; } v; v.f = f;
  unsigned int u = v.u;
  u += 0x7fffu + ((u >> 16) & 1u);   // round-to-nearest-even
  return (unsigned short)(u >> 16);
}
DEVI float bf2f(unsigned short h) {
  union { unsigned int u; float f; } v; v.u = ((unsigned int)h) << 16;
  return v.f;
}

DEVI void gld_lds16(const void* g, void* l) {
  __builtin_amdgcn_global_load_lds(
      (const __attribute__((address_space(1))) void*)g,
      (__attribute__((address_space(3))) void*)l, 16, 0, 0);
}

DEVI unsigned int cvt_pk_bf16(float lo, float hi) {
  unsigned int r;
  asm("v_cvt_pk_bf16_f32 %0, %1, %2" : "=v"(r) : "v"(lo), "v"(hi));
  return r;
}

DEVI float exp2_raw(float x) {  // single v_exp_f32 (HW exp2), no libm fixup
  float r;
  asm("v_exp_f32 %0, %1" : "=v"(r) : "v"(x));
  return r;
}

#define MFMA16(a, b, c) __builtin_amdgcn_mfma_f32_16x16x32_bf16((a), (b), (c), 0, 0, 0)
#define MFMA32(a, b, c) __builtin_amdgcn_mfma_f32_32x32x16_bf16((a), (b), (c), 0, 0, 0)

// q scale folded with log2(e) so softmax runs in exp2 domain
#define QSCALE 0.18033688011112042f  // 0.125 * log2(e)

// ---------------------------------------------------------------- convert (fused)
// one dispatch converts x, qkv_w, proj_w (fp32 -> bf16), segmented by index
__global__ void __launch_bounds__(256) convert3_kernel(
    const float* __restrict__ x, const float* __restrict__ qkv_w,
    const float* __restrict__ proj_w,
    unsigned short* __restrict__ xb, unsigned short* __restrict__ wqkv,
    unsigned short* __restrict__ wproj) {
  const int i = blockIdx.x * 256 + threadIdx.x;  // grid covers 2162688 quads
  const float* src; unsigned short* dst; int off;
  if (i < 1572864)      { src = x;      dst = xb;    off = i; }
  else if (i < 2015232) { src = qkv_w;  dst = wqkv;  off = i - 1572864; }
  else                  { src = proj_w; dst = wproj; off = i - 2015232; }
  float4 v = ((const float4*)src)[off];
  ushort4 o;
  o.x = f2bf(v.x); o.y = f2bf(v.y); o.z = f2bf(v.z); o.w = f2bf(v.w);
  ((ushort4*)dst)[off] = o;
}

// ---------------------------------------------------------------- GEMM (NT)
// R9 configuration (best measured: 48.4us QKV) — 128x128 tile, BK=64,
// source-swizzled global_load_lds, double-buffered, counted vmcnt:
//   stage(buf^1, t+1); s_waitcnt vmcnt(8)   <- retires ONLY tile t's loads,
//   barrier; compute(buf);                      t+1's 8 stay in flight
//   lgkmcnt(0); barrier                     <- frees buf for restage
// MODE 0: QKV epilogue -> Q*(0.125*log2e) [bh][n][64], K [bh][n][64], V^T [bh][64][1024]
// MODE 1: proj epilogue (+bias, fp32 out [M][768])
template <int MODE>
__global__ void __launch_bounds__(256) gemm_nt(
    const unsigned short* __restrict__ A,
    const unsigned short* __restrict__ Bw,
    unsigned short* __restrict__ oq,
    unsigned short* __restrict__ okk,
    unsigned short* __restrict__ ovt,
    float* __restrict__ of,
    const float* __restrict__ bias) {
  constexpr int K = 768;
  constexpr int NT = K / 64;  // 12 K-tiles
  const int tid = threadIdx.x;
  const int l = tid & 63, wv = tid >> 6;
  const int wy = wv >> 1, wx = wv & 1;
  const int lg = l >> 4, lr = l & 15;
  const int m0 = blockIdx.x * 128, n0 = blockIdx.y * 128;

  __shared__ __align__(16) unsigned short As[2][128 * 64];
  __shared__ __align__(16) unsigned short Bs[2][128 * 64];

  f32x4 acc[4][4] = {};

  // stage one 128x64 tile pair; row = 128B = 8 granules of 16B; src pre-swizzled
  auto stage = [&](int buf, int k0) {
#pragma unroll
    for (int c = 0; c < 4; ++c) {
      const int row = c * 32 + wv * 8 + (l >> 3);
      const int g = l & 7;
      const int off = ((g ^ (row & 7)) * 8);
      gld_lds16(A + (size_t)(m0 + row) * K + k0 + off, &As[buf][(c * 32 + wv * 8) * 64]);
      gld_lds16(Bw + (size_t)(n0 + row) * K + k0 + off, &Bs[buf][(c * 32 + wv * 8) * 64]);
    }
  };

  stage(0, 0);  // 8 loads in flight

  int cur = 0;
  for (int t = 0; t < NT; ++t) {
    if (t + 1 < NT) {
      stage(cur ^ 1, (t + 1) * 64);  // +8 -> 16 outstanding
      asm volatile("s_waitcnt vmcnt(8)" ::: "memory");  // tile t landed; t+1 in flight
    } else {
      asm volatile("s_waitcnt vmcnt(0)" ::: "memory");  // tail
    }
    __builtin_amdgcn_s_barrier();
    __builtin_amdgcn_sched_barrier(0);

#pragma unroll
    for (int kk = 0; kk < 2; ++kk) {
      bf16x8 af[4], bfr[4];
#pragma unroll
      for (int i = 0; i < 4; ++i) {
        const int row = wy * 64 + i * 16 + lr;
        af[i] = *(const bf16x8*)&As[cur][row * 64 + (((kk * 4 + lg) ^ (row & 7)) * 8)];
      }
#pragma unroll
      for (int j = 0; j < 4; ++j) {
        const int row = wx * 64 + j * 16 + lr;
        bfr[j] = *(const bf16x8*)&Bs[cur][row * 64 + (((kk * 4 + lg) ^ (row & 7)) * 8)];
      }
#pragma unroll
      for (int i = 0; i < 4; ++i) {
#pragma unroll
        for (int j = 0; j < 4; ++j)
          acc[i][j] = MFMA16(af[i], bfr[j], acc[i][j]);
      }
    }

    // own ds_reads of buf[cur] consumed; barrier releases it for restaging
    asm volatile("s_waitcnt lgkmcnt(0)" ::: "memory");
    __builtin_amdgcn_sched_barrier(0);
    __builtin_amdgcn_s_barrier();
    cur ^= 1;
  }

  if constexpr (MODE == 0) {
    const int t = n0 / 768;  // 0:q 1:k 2:v (768 % 128 == 0 -> uniform per block)
    if (t < 2) {
      unsigned short* base = (t == 0) ? oq : okk;
      const float sc = (t == 0) ? QSCALE : 1.0f;
#pragma unroll
      for (int i = 0; i < 4; ++i) {
        const int m = m0 + wy * 64 + i * 16 + lg * 4;
#pragma unroll
        for (int j = 0; j < 4; ++j) {
          const int col = n0 + wx * 64 + j * 16 + lr;
          const int rem = col - t * 768;
          const int h = rem >> 6, d = rem & 63;
#pragma unroll
          for (int r = 0; r < 4; ++r) {
            const int mm = m + r;
            const int b = mm >> 10, n = mm & 1023;
            base[(((size_t)(b * 12 + h) << 10) + n) * 64 + d] = f2bf(acc[i][j][r] * sc);
          }
        }
      }
    } else {
      // V^T [bh][d][n] bf16, packed quad stores along n
#pragma unroll
      for (int i = 0; i < 4; ++i) {
        const int m = m0 + wy * 64 + i * 16 + lg * 4;
        const int b = m >> 10, ntok = m & 1023;
#pragma unroll
        for (int j = 0; j < 4; ++j) {
          const int col = n0 + wx * 64 + j * 16 + lr;
          const int rem = col - 1536;
          const int h = rem >> 6, d = rem & 63;
          ushort4 pk4;
          pk4.x = f2bf(acc[i][j][0]); pk4.y = f2bf(acc[i][j][1]);
          pk4.z = f2bf(acc[i][j][2]); pk4.w = f2bf(acc[i][j][3]);
          *(ushort4*)(ovt + ((size_t)(b * 12 + h) * 64 + d) * 1024 + ntok) = pk4;
        }
      }
    }
  } else {
#pragma unroll
    for (int i = 0; i < 4; ++i) {
      const int m = m0 + wy * 64 + i * 16 + lg * 4;
#pragma unroll
      for (int j = 0; j < 4; ++j) {
        const int col = n0 + wx * 64 + j * 16 + lr;
        const float bv = bias[col];
#pragma unroll
        for (int r = 0; r < 4; ++r)
          of[(size_t)(m + r) * 768 + col] = acc[i][j][r] + bv;
      }
    }
  }
}

// ---------------------------------------------------------------- rel bias (MFMA)
// Batched 32x32x64 GEMMs, zero LDS.
// rel_h (per bh, y):  D[kh][x] = sum_c rph[y+31-kh][c] * Q[y*32+x][c]
// rel_w (per bh, x):  D[kw][y] = sum_c rpw[x+31-kw][c] * Q[y*32+x][c]
// Outputs TRANSPOSED bf16: relh_t[bh][kh][n], relw_t[bh][kw][n], n = y*32+x.
// (Q pre-scaled by 0.125*log2e, so bias lands in exp2 domain automatically.)
__global__ void __launch_bounds__(256) rel_kernel(
    const unsigned short* __restrict__ Q,  // [96][1024][64] bf16 (scaled)
    const float* __restrict__ rph,         // [63][64] f32
    const float* __restrict__ rpw,         // [63][64] f32
    unsigned short* __restrict__ relh_t,   // [96][32][1024] bf16
    unsigned short* __restrict__ relw_t) {
  const int bh = blockIdx.y;
  const int tid = threadIdx.x;
  const int l = tid & 63, w = tid >> 6;
  const int hi = l >> 5, l31 = l & 31;
  const int yx = blockIdx.x * 4 + w;  // 0..31: y for the rel_h tile, x for rel_w

  const unsigned short* Qb = Q + (size_t)bh * 65536;

  // ---- rel_h tile: A rows = rph table (f32 -> bf16 in reg), B cols = Q rows
  f32x16 acch = {};
#pragma unroll
  for (int s4 = 0; s4 < 4; ++s4) {
    const float* ar = rph + (yx + 31 - l31) * 64 + s4 * 16 + hi * 8;
    float4 fa = ((const float4*)ar)[0], fb = ((const float4*)ar)[1];
    union { unsigned int u[4]; bf16x8 v; } au;
    au.u[0] = cvt_pk_bf16(fa.x, fa.y); au.u[1] = cvt_pk_bf16(fa.z, fa.w);
    au.u[2] = cvt_pk_bf16(fb.x, fb.y); au.u[3] = cvt_pk_bf16(fb.z, fb.w);
    bf16x8 qv = *(const bf16x8*)(Qb + (size_t)(yx * 32 + l31) * 64 + s4 * 16 + hi * 8);
    acch = MFMA32(au.v, qv, acch);
  }
  {
    unsigned short* ob = relh_t + (size_t)bh * 32768 + yx * 32 + l31;
#pragma unroll
    for (int r = 0; r < 16; ++r) {
      const int kh = (r & 3) + 8 * (r >> 2) + 4 * hi;
      ob[(size_t)kh * 1024] = f2bf(acch[r]);
    }
  }

  // ---- rel_w tile: A rows = rpw table, B cols = Q rows n = y*32 + yx (y = l31)
  f32x16 accw = {};
#pragma unroll
  for (int s4 = 0; s4 < 4; ++s4) {
    const float* ar = rpw + (yx + 31 - l31) * 64 + s4 * 16 + hi * 8;
    float4 fa = ((const float4*)ar)[0], fb = ((const float4*)ar)[1];
    union { unsigned int u[4]; bf16x8 v; } au;
    au.u[0] = cvt_pk_bf16(fa.x, fa.y); au.u[1] = cvt_pk_bf16(fa.z, fa.w);
    au.u[2] = cvt_pk_bf16(fb.x, fb.y); au.u[3] = cvt_pk_bf16(fb.z, fb.w);
    bf16x8 qv = *(const bf16x8*)(Qb + (size_t)(l31 * 32 + yx) * 64 + s4 * 16 + hi * 8);
    accw = MFMA32(au.v, qv, accw);
  }
  {
    unsigned short* ob = relw_t + (size_t)bh * 32768 + l31 * 32 + yx;
#pragma unroll
    for (int r = 0; r < 16; ++r) {
      const int kw = (r & 3) + 8 * (r >> 2) + 4 * hi;
      ob[(size_t)kw * 1024] = f2bf(accw[r]);
    }
  }
}

// ---------------------------------------------------------------- flash attn
// ZERO-LDS / ZERO-BARRIER version. Rationale (m168/m169 lesson: don't stage
// what cache-fits): the MFMA A-operand fragment pattern depends only on
// lane&31 — all 4 waves read IDENTICAL K/V fragments, so LDS staging was a 4x
// LDS-read waste; the 8KB K and V tiles are L1-resident and shared by the
// block's waves when read directly global->VGPR. V-loads issue before
// QK^T+softmax (~400cyc) so their latency hides; no __syncthreads anywhere,
// waves free-run (TLP covers K-load head latency).
// Swapped QK^T (32x32x16): lane holds P[q=lane&31][32 k's] in regs; no
// max-stabilization (logits bounded); rel_w bias via identity-MFMA C-operand;
// row-sums on the MFMA pipe (ones x P); raw v_exp_f32; P->bf16 via
// cvt_pk+permlane32_swap feeds PV directly.
__global__ void __launch_bounds__(256, 2) attn_kernel(
    const unsigned short* __restrict__ Q,      // [96][1024][64] bf16 (scaled)
    const unsigned short* __restrict__ Km,     // [96][1024][64] bf16
    const unsigned short* __restrict__ VT,     // [96][64][1024] bf16
    const unsigned short* __restrict__ relh_t, // [96][32][1024] bf16
    const unsigned short* __restrict__ relw_t, // [96][32][1024] bf16
    unsigned short* __restrict__ out) {        // [8][1024][768] bf16
  const int bid = blockIdx.x;      // 768 = 8 qt x 96 bh, bh fastest -> XCD locality
  const int qt = bid / 96;
  const int bh = bid % 96;
  const int q0 = qt * 128;
  const int tid = threadIdx.x;
  const int l = tid & 63, w = tid >> 6;
  const int hi = l >> 5, l31 = l & 31;

  const unsigned short* Kb = Km + (size_t)bh * 65536 + (size_t)l31 * 64 + hi * 8;
  const unsigned short* Vb = VT + (size_t)bh * 65536 + (size_t)l31 * 1024 + hi * 8;
  const unsigned short* rhb = relh_t + (size_t)bh * 32768 + q0 + w * 32 + l31;

  // Q fragments (B operand): lane holds Q[q=lane&31][d = s4*16 + hi*8 + e]
  bf16x8 qf[4];
  {
    const unsigned short* qp =
        Q + (size_t)bh * 65536 + (size_t)(q0 + w * 32 + l31) * 64 + hi * 8;
#pragma unroll
    for (int s4 = 0; s4 < 4; ++s4) qf[s4] = *(const bf16x8*)(qp + s4 * 16);
  }

  // ---- rw bias acc via identity-fragment MFMA (once):
  // rwacc[r](q) = relw_t[crow(r,hi)][q]; used as C-input of each tile's first
  // QK^T MFMA -> per-tile rel_w bias costs ZERO VALU.
  f32x16 rwacc;
  bf16x8 onesA;
  {
    bf16x8 idA0, idA1, rwB0, rwB1;
    const short onebf = (short)0x3F80;
#pragma unroll
    for (int e = 0; e < 8; ++e) {
      idA0[e] = (l31 == hi * 8 + e) ? onebf : (short)0;
      idA1[e] = (l31 == 16 + hi * 8 + e) ? onebf : (short)0;
      onesA[e] = onebf;
      rwB0[e] = (short)relw_t[(size_t)bh * 32768 + (size_t)(hi * 8 + e) * 1024 +
                              q0 + w * 32 + l31];
      rwB1[e] = (short)relw_t[(size_t)bh * 32768 + (size_t)(16 + hi * 8 + e) * 1024 +
                              q0 + w * 32 + l31];
    }
    f32x16 z = {};
    rwacc = MFMA32(idA0, rwB0, z);
    rwacc = MFMA32(idA1, rwB1, rwacc);
  }

  f32x16 od0 = {}, od1 = {}, sumacc = {};

  for (int t = 0; t < 16; ++t) {
    const int kv0 = t << 6;

    // ---- K fragments direct from global (L1-shared across the 4 waves)
    bf16x8 kf0[4], kf1[4];
#pragma unroll
    for (int s4 = 0; s4 < 4; ++s4) {
      kf0[s4] = *(const bf16x8*)(Kb + (size_t)kv0 * 64 + s4 * 16);
      kf1[s4] = *(const bf16x8*)(Kb + (size_t)kv0 * 64 + 2048 + s4 * 16);
    }
    // ---- V fragments issued NOW; consumed after QK^T+softmax (~400cyc later)
    bf16x8 vf0[4], vf1[4];
#pragma unroll
    for (int ks = 0; ks < 4; ++ks) {
      vf0[ks] = *(const bf16x8*)(Vb + kv0 + ks * 16);
      vf1[ks] = *(const bf16x8*)(Vb + 32768 + kv0 + ks * 16);
    }
    const float rh0 = bf2f(rhb[(size_t)(2 * t) * 1024]);
    const float rh1 = bf2f(rhb[(size_t)(2 * t + 1) * 1024]);

    // ---- S^T = K Q^T + rw-bias : D[k][q], lane: q = lane&31, k = crow(r,hi)
    f32x16 s0 = MFMA32(kf0[0], qf[0], rwacc);
    f32x16 s1 = MFMA32(kf1[0], qf[0], rwacc);
#pragma unroll
    for (int s4 = 1; s4 < 4; ++s4) {
      s0 = MFMA32(kf0[s4], qf[s4], s0);
      s1 = MFMA32(kf1[s4], qf[s4], s1);
    }

    // ---- P = exp2(S + rh) directly (no max-sub; logits bounded), rh per half
#pragma unroll
    for (int r = 0; r < 16; ++r) {
      s0[r] = exp2_raw(s0[r] + rh0);
      s1[r] = exp2_raw(s1[r] + rh1);
    }

    // ---- P -> bf16 B-operand fragments via cvt_pk + permlane32_swap (T12)
    bf16x8 pa[4];
#pragma unroll
    for (int ks = 0; ks < 4; ++ks) {
      unsigned int c0, c1, c2, c3;
      if (ks == 0) {
        c0 = cvt_pk_bf16(s0[0], s0[1]);  c1 = cvt_pk_bf16(s0[2], s0[3]);
        c2 = cvt_pk_bf16(s0[4], s0[5]);  c3 = cvt_pk_bf16(s0[6], s0[7]);
      } else if (ks == 1) {
        c0 = cvt_pk_bf16(s0[8], s0[9]);  c1 = cvt_pk_bf16(s0[10], s0[11]);
        c2 = cvt_pk_bf16(s0[12], s0[13]); c3 = cvt_pk_bf16(s0[14], s0[15]);
      } else if (ks == 2) {
        c0 = cvt_pk_bf16(s1[0], s1[1]);  c1 = cvt_pk_bf16(s1[2], s1[3]);
        c2 = cvt_pk_bf16(s1[4], s1[5]);  c3 = cvt_pk_bf16(s1[6], s1[7]);
      } else {
        c0 = cvt_pk_bf16(s1[8], s1[9]);  c1 = cvt_pk_bf16(s1[10], s1[11]);
        c2 = cvt_pk_bf16(s1[12], s1[13]); c3 = cvt_pk_bf16(s1[14], s1[15]);
      }
      uint2v x = __builtin_amdgcn_permlane32_swap(c0, c2, false, false);
      uint2v z = __builtin_amdgcn_permlane32_swap(c1, c3, false, false);
      union { unsigned int u[4]; bf16x8 v; } uu;
      uu.u[0] = x.x; uu.u[1] = z.x; uu.u[2] = x.y; uu.u[3] = z.y;
      pa[ks] = uu.v;
    }

    // ---- O += V^T P^T and row-sums += ones x P (sum on the MFMA pipe)
#pragma unroll
    for (int ks = 0; ks < 4; ++ks) {
      od0 = MFMA32(vf0[ks], pa[ks], od0);
      od1 = MFMA32(vf1[ks], pa[ks], od1);
      sumacc = MFMA32(onesA, pa[ks], sumacc);
    }
  }

  // ---- epilogue: every sumacc row = full row-sum for q = lane&31
  const float inv = 1.f / sumacc[0];
  const int b = bh / 12, h = bh % 12;
  const int n = q0 + w * 32 + l31;
  unsigned short* ob = out + ((size_t)(b * 1024 + n)) * 768 + h * 64;
#pragma unroll
  for (int r4 = 0; r4 < 4; ++r4) {
    ushort4 p0, p1;
    p0.x = f2bf(od0[r4 * 4 + 0] * inv); p0.y = f2bf(od0[r4 * 4 + 1] * inv);
    p0.z = f2bf(od0[r4 * 4 + 2] * inv); p0.w = f2bf(od0[r4 * 4 + 3] * inv);
    p1.x = f2bf(od1[r4 * 4 + 0] * inv); p1.y = f2bf(od1[r4 * 4 + 1] * inv);
    p1.z = f2bf(od1[r4 * 4 + 2] * inv); p1.w = f2bf(od1[r4 * 4 + 3] * inv);
    *(ushort4*)(ob + 8 * r4 + 4 * hi) = p0;
    *(ushort4*)(ob + 32 + 8 * r4 + 4 * hi) = p1;
  }
}

// ---------------------------------------------------------------- launch
extern "C" void kernel_launch(void* const* d_in, const int* in_sizes, int n_in,
                              void* d_out, int out_size, void* d_ws, size_t ws_size,
                              hipStream_t stream) {
  const float* x      = (const float*)d_in[0];
  const float* qkv_w  = (const float*)d_in[1];
  const float* rph    = (const float*)d_in[2];
  const float* rpw    = (const float*)d_in[3];
  const float* proj_w = (const float*)d_in[4];
  const float* proj_b = (const float*)d_in[5];
  float* out = (float*)d_out;

  char* ws = (char*)d_ws;
  unsigned short* xb     = (unsigned short*)(ws);              // 12,582,912 B (reused as attn_out)
  unsigned short* wqkv   = (unsigned short*)(ws + 12582912);   //  3,538,944 B
  unsigned short* wproj  = (unsigned short*)(ws + 16121856);   //  1,179,648 B
  unsigned short* qb     = (unsigned short*)(ws + 17301504);   // 12,582,912 B
  unsigned short* kb     = (unsigned short*)(ws + 29884416);   // 12,582,912 B
  unsigned short* vbT    = (unsigned short*)(ws + 42467328);   // 12,582,912 B
  unsigned short* relh_t = (unsigned short*)(ws + 55050240);   //  6,291,456 B
  unsigned short* relw_t = (unsigned short*)(ws + 61341696);   //  6,291,456 B (end 67,633,152)

  convert3_kernel<<<8448, 256, 0, stream>>>(x, qkv_w, proj_w, xb, wqkv, wproj);

  gemm_nt<0><<<dim3(64, 18), 256, 0, stream>>>(xb, wqkv, qb, kb, vbT, nullptr, nullptr);

  rel_kernel<<<dim3(8, 96), 256, 0, stream>>>(qb, rph, rpw, relh_t, relw_t);

  attn_kernel<<<768, 256, 0, stream>>>(qb, kb, vbT, relh_t, relw_t, xb);

  gemm_nt<1><<<dim3(64, 6), 256, 0, stream>>>(xb, wproj, nullptr, nullptr, nullptr, out, proj_b);
}

// Round 13
// 138.886 us; speedup vs baseline: 1.3774x; 1.3774x over previous
//
#include <hip/hip_runtime.h>

#define DEVI __device__ __forceinline__

typedef float f32x4 __attribute__((ext_vector_type(4)));
typedef float f32x16 __attribute__((ext_vector_type(16)));
typedef short bf16x8 __attribute__((ext_vector_type(8)));
typedef unsigned int uint2v __attribute__((ext_vector_type(2)));

DEVI unsigned short f2bf(float f) {
  union { float f; unsigned int u; } v; v.f = f;
  unsigned int u = v.u;
  u += 0x7fffu + ((u >> 16) & 1u);   // round-to-nearest-even
  return (unsigned short)(u >> 16);
}
DEVI float bf2f(unsigned short h) {
  union { unsigned int u; float f; } v; v.u = ((unsigned int)h) << 16;
  return v.f;
}

DEVI void gld_lds16(const void* g, void* l) {
  __builtin_amdgcn_global_load_lds(
      (const __attribute__((address_space(1))) void*)g,
      (__attribute__((address_space(3))) void*)l, 16, 0, 0);
}

DEVI unsigned int cvt_pk_bf16(float lo, float hi) {
  unsigned int r;
  asm("v_cvt_pk_bf16_f32 %0, %1, %2" : "=v"(r) : "v"(lo), "v"(hi));
  return r;
}

DEVI float exp2_raw(float x) {  // single v_exp_f32 (HW exp2), no libm fixup
  float r;
  asm("v_exp_f32 %0, %1" : "=v"(r) : "v"(x));
  return r;
}

#define MFMA16(a, b, c) __builtin_amdgcn_mfma_f32_16x16x32_bf16((a), (b), (c), 0, 0, 0)
#define MFMA32(a, b, c) __builtin_amdgcn_mfma_f32_32x32x16_bf16((a), (b), (c), 0, 0, 0)

// q scale folded with log2(e) so softmax runs in exp2 domain
#define QSCALE 0.18033688011112042f  // 0.125 * log2(e)

// ---------------------------------------------------------------- convert (fused)
// one dispatch converts x, qkv_w, proj_w (fp32 -> bf16), segmented by index
__global__ void __launch_bounds__(256) convert3_kernel(
    const float* __restrict__ x, const float* __restrict__ qkv_w,
    const float* __restrict__ proj_w,
    unsigned short* __restrict__ xb, unsigned short* __restrict__ wqkv,
    unsigned short* __restrict__ wproj) {
  const int i = blockIdx.x * 256 + threadIdx.x;  // grid covers 2162688 quads
  const float* src; unsigned short* dst; int off;
  if (i < 1572864)      { src = x;      dst = xb;    off = i; }
  else if (i < 2015232) { src = qkv_w;  dst = wqkv;  off = i - 1572864; }
  else                  { src = proj_w; dst = wproj; off = i - 2015232; }
  float4 v = ((const float4*)src)[off];
  ushort4 o;
  o.x = f2bf(v.x); o.y = f2bf(v.y); o.z = f2bf(v.z); o.w = f2bf(v.w);
  ((ushort4*)dst)[off] = o;
}

// ---------------------------------------------------------------- GEMM (NT)
// R9 configuration (best measured: 48.4us QKV) — 128x128 tile, BK=64,
// source-swizzled global_load_lds, double-buffered, counted vmcnt:
//   stage(buf^1, t+1); s_waitcnt vmcnt(8)   <- retires ONLY tile t's loads,
//   barrier; compute(buf);                      t+1's 8 stay in flight
//   lgkmcnt(0); barrier                     <- frees buf for restage
// MODE 0: QKV epilogue -> Q*(0.125*log2e) [bh][n][64], K [bh][n][64], V^T [bh][64][1024]
// MODE 1: proj epilogue (+bias, fp32 out [M][768])
template <int MODE>
__global__ void __launch_bounds__(256) gemm_nt(
    const unsigned short* __restrict__ A,
    const unsigned short* __restrict__ Bw,
    unsigned short* __restrict__ oq,
    unsigned short* __restrict__ okk,
    unsigned short* __restrict__ ovt,
    float* __restrict__ of,
    const float* __restrict__ bias) {
  constexpr int K = 768;
  constexpr int NT = K / 64;  // 12 K-tiles
  const int tid = threadIdx.x;
  const int l = tid & 63, wv = tid >> 6;
  const int wy = wv >> 1, wx = wv & 1;
  const int lg = l >> 4, lr = l & 15;
  const int m0 = blockIdx.x * 128, n0 = blockIdx.y * 128;

  __shared__ __align__(16) unsigned short As[2][128 * 64];
  __shared__ __align__(16) unsigned short Bs[2][128 * 64];

  f32x4 acc[4][4] = {};

  // stage one 128x64 tile pair; row = 128B = 8 granules of 16B; src pre-swizzled
  auto stage = [&](int buf, int k0) {
#pragma unroll
    for (int c = 0; c < 4; ++c) {
      const int row = c * 32 + wv * 8 + (l >> 3);
      const int g = l & 7;
      const int off = ((g ^ (row & 7)) * 8);
      gld_lds16(A + (size_t)(m0 + row) * K + k0 + off, &As[buf][(c * 32 + wv * 8) * 64]);
      gld_lds16(Bw + (size_t)(n0 + row) * K + k0 + off, &Bs[buf][(c * 32 + wv * 8) * 64]);
    }
  };

  stage(0, 0);  // 8 loads in flight

  int cur = 0;
  for (int t = 0; t < NT; ++t) {
    if (t + 1 < NT) {
      stage(cur ^ 1, (t + 1) * 64);  // +8 -> 16 outstanding
      asm volatile("s_waitcnt vmcnt(8)" ::: "memory");  // tile t landed; t+1 in flight
    } else {
      asm volatile("s_waitcnt vmcnt(0)" ::: "memory");  // tail
    }
    __builtin_amdgcn_s_barrier();
    __builtin_amdgcn_sched_barrier(0);

#pragma unroll
    for (int kk = 0; kk < 2; ++kk) {
      bf16x8 af[4], bfr[4];
#pragma unroll
      for (int i = 0; i < 4; ++i) {
        const int row = wy * 64 + i * 16 + lr;
        af[i] = *(const bf16x8*)&As[cur][row * 64 + (((kk * 4 + lg) ^ (row & 7)) * 8)];
      }
#pragma unroll
      for (int j = 0; j < 4; ++j) {
        const int row = wx * 64 + j * 16 + lr;
        bfr[j] = *(const bf16x8*)&Bs[cur][row * 64 + (((kk * 4 + lg) ^ (row & 7)) * 8)];
      }
#pragma unroll
      for (int i = 0; i < 4; ++i) {
#pragma unroll
        for (int j = 0; j < 4; ++j)
          acc[i][j] = MFMA16(af[i], bfr[j], acc[i][j]);
      }
    }

    // own ds_reads of buf[cur] consumed; barrier releases it for restaging
    asm volatile("s_waitcnt lgkmcnt(0)" ::: "memory");
    __builtin_amdgcn_sched_barrier(0);
    __builtin_amdgcn_s_barrier();
    cur ^= 1;
  }

  if constexpr (MODE == 0) {
    const int t = n0 / 768;  // 0:q 1:k 2:v (768 % 128 == 0 -> uniform per block)
    if (t < 2) {
      unsigned short* base = (t == 0) ? oq : okk;
      const float sc = (t == 0) ? QSCALE : 1.0f;
#pragma unroll
      for (int i = 0; i < 4; ++i) {
        const int m = m0 + wy * 64 + i * 16 + lg * 4;
#pragma unroll
        for (int j = 0; j < 4; ++j) {
          const int col = n0 + wx * 64 + j * 16 + lr;
          const int rem = col - t * 768;
          const int h = rem >> 6, d = rem & 63;
#pragma unroll
          for (int r = 0; r < 4; ++r) {
            const int mm = m + r;
            const int b = mm >> 10, n = mm & 1023;
            base[(((size_t)(b * 12 + h) << 10) + n) * 64 + d] = f2bf(acc[i][j][r] * sc);
          }
        }
      }
    } else {
      // V^T [bh][d][n] bf16, packed quad stores along n
#pragma unroll
      for (int i = 0; i < 4; ++i) {
        const int m = m0 + wy * 64 + i * 16 + lg * 4;
        const int b = m >> 10, ntok = m & 1023;
#pragma unroll
        for (int j = 0; j < 4; ++j) {
          const int col = n0 + wx * 64 + j * 16 + lr;
          const int rem = col - 1536;
          const int h = rem >> 6, d = rem & 63;
          ushort4 pk4;
          pk4.x = f2bf(acc[i][j][0]); pk4.y = f2bf(acc[i][j][1]);
          pk4.z = f2bf(acc[i][j][2]); pk4.w = f2bf(acc[i][j][3]);
          *(ushort4*)(ovt + ((size_t)(b * 12 + h) * 64 + d) * 1024 + ntok) = pk4;
        }
      }
    }
  } else {
#pragma unroll
    for (int i = 0; i < 4; ++i) {
      const int m = m0 + wy * 64 + i * 16 + lg * 4;
#pragma unroll
      for (int j = 0; j < 4; ++j) {
        const int col = n0 + wx * 64 + j * 16 + lr;
        const float bv = bias[col];
#pragma unroll
        for (int r = 0; r < 4; ++r)
          of[(size_t)(m + r) * 768 + col] = acc[i][j][r] + bv;
      }
    }
  }
}

// ---------------------------------------------------------------- rel bias (MFMA)
// Batched 32x32x64 GEMMs, zero LDS.
// rel_h (per bh, y):  D[kh][x] = sum_c rph[y+31-kh][c] * Q[y*32+x][c]
// rel_w (per bh, x):  D[kw][y] = sum_c rpw[x+31-kw][c] * Q[y*32+x][c]
// Outputs TRANSPOSED bf16: relh_t[bh][kh][n], relw_t[bh][kw][n], n = y*32+x.
// (Q pre-scaled by 0.125*log2e, so bias lands in exp2 domain automatically.)
__global__ void __launch_bounds__(256) rel_kernel(
    const unsigned short* __restrict__ Q,  // [96][1024][64] bf16 (scaled)
    const float* __restrict__ rph,         // [63][64] f32
    const float* __restrict__ rpw,         // [63][64] f32
    unsigned short* __restrict__ relh_t,   // [96][32][1024] bf16
    unsigned short* __restrict__ relw_t) {
  const int bh = blockIdx.y;
  const int tid = threadIdx.x;
  const int l = tid & 63, w = tid >> 6;
  const int hi = l >> 5, l31 = l & 31;
  const int yx = blockIdx.x * 4 + w;  // 0..31: y for the rel_h tile, x for rel_w

  const unsigned short* Qb = Q + (size_t)bh * 65536;

  // ---- rel_h tile: A rows = rph table (f32 -> bf16 in reg), B cols = Q rows
  f32x16 acch = {};
#pragma unroll
  for (int s4 = 0; s4 < 4; ++s4) {
    const float* ar = rph + (yx + 31 - l31) * 64 + s4 * 16 + hi * 8;
    float4 fa = ((const float4*)ar)[0], fb = ((const float4*)ar)[1];
    union { unsigned int u[4]; bf16x8 v; } au;
    au.u[0] = cvt_pk_bf16(fa.x, fa.y); au.u[1] = cvt_pk_bf16(fa.z, fa.w);
    au.u[2] = cvt_pk_bf16(fb.x, fb.y); au.u[3] = cvt_pk_bf16(fb.z, fb.w);
    bf16x8 qv = *(const bf16x8*)(Qb + (size_t)(yx * 32 + l31) * 64 + s4 * 16 + hi * 8);
    acch = MFMA32(au.v, qv, acch);
  }
  {
    unsigned short* ob = relh_t + (size_t)bh * 32768 + yx * 32 + l31;
#pragma unroll
    for (int r = 0; r < 16; ++r) {
      const int kh = (r & 3) + 8 * (r >> 2) + 4 * hi;
      ob[(size_t)kh * 1024] = f2bf(acch[r]);
    }
  }

  // ---- rel_w tile: A rows = rpw table, B cols = Q rows n = y*32 + yx (y = l31)
  f32x16 accw = {};
#pragma unroll
  for (int s4 = 0; s4 < 4; ++s4) {
    const float* ar = rpw + (yx + 31 - l31) * 64 + s4 * 16 + hi * 8;
    float4 fa = ((const float4*)ar)[0], fb = ((const float4*)ar)[1];
    union { unsigned int u[4]; bf16x8 v; } au;
    au.u[0] = cvt_pk_bf16(fa.x, fa.y); au.u[1] = cvt_pk_bf16(fa.z, fa.w);
    au.u[2] = cvt_pk_bf16(fb.x, fb.y); au.u[3] = cvt_pk_bf16(fb.z, fb.w);
    bf16x8 qv = *(const bf16x8*)(Qb + (size_t)(l31 * 32 + yx) * 64 + s4 * 16 + hi * 8);
    accw = MFMA32(au.v, qv, accw);
  }
  {
    unsigned short* ob = relw_t + (size_t)bh * 32768 + l31 * 32 + yx;
#pragma unroll
    for (int r = 0; r < 16; ++r) {
      const int kw = (r & 3) + 8 * (r >> 2) + 4 * hi;
      ob[(size_t)kw * 1024] = f2bf(accw[r]);
    }
  }
}

// ---------------------------------------------------------------- flash attn
// 4 waves x 32 q-rows = 128 q per block; KVBLK=64, double-buffered K/V^T LDS
// (R12 post-mortem: zero-LDS was latency-bound, 2x worse — LDS staging's value
// is latency DECOUPLING, reverted). T4 counted vmcnt: stage(t+1) at top,
// vmcnt(4) retires only tile t's loads (t+1's 4 stay in flight across the
// whole compute phase), lgkmcnt(0)+barrier frees the buffer. T5 setprio(1)
// around MFMA clusters. Swapped QK^T (32x32x16): lane holds P[q=lane&31][32k]
// in regs; no max-stabilization (logits bounded); rel_w bias via identity-MFMA
// C-operand; row-sums on the MFMA pipe; raw v_exp_f32; P->bf16 via
// cvt_pk+permlane32_swap feeds PV directly.
__global__ void __launch_bounds__(256, 3) attn_kernel(
    const unsigned short* __restrict__ Q,      // [96][1024][64] bf16 (scaled)
    const unsigned short* __restrict__ Km,     // [96][1024][64] bf16
    const unsigned short* __restrict__ VT,     // [96][64][1024] bf16
    const unsigned short* __restrict__ relh_t, // [96][32][1024] bf16
    const unsigned short* __restrict__ relw_t, // [96][32][1024] bf16
    unsigned short* __restrict__ out) {        // [8][1024][768] bf16
  const int bid = blockIdx.x;      // 768 = 8 qt x 96 bh, bh fastest -> XCD locality
  const int qt = bid / 96;
  const int bh = bid % 96;
  const int q0 = qt * 128;
  const int tid = threadIdx.x;
  const int l = tid & 63, w = tid >> 6;
  const int hi = l >> 5, l31 = l & 31;

  __shared__ __align__(16) unsigned short Ks[2][64 * 64];   // [k][d], src-swizzled
  __shared__ __align__(16) unsigned short VTs[2][64 * 64];  // [d][k], src-swizzled
  __shared__ __align__(16) unsigned short rhsL[32 * 128];   // [kh][q-local]

  const unsigned short* Kb = Km + (size_t)bh * 65536;
  const unsigned short* Vb = VT + (size_t)bh * 65536;

  // stage rel_h rows for this block's 128 q (linear LDS) — oldest in vm queue
#pragma unroll
  for (int c = 0; c < 2; ++c) {
    const int row = c * 16 + w * 4 + (l >> 4);
    gld_lds16(relh_t + (size_t)bh * 32768 + (size_t)row * 1024 + q0 + (l & 15) * 8,
              &rhsL[(c * 16 + w * 4) * 128]);
  }

  auto stage = [&](int buf, int t) {  // 4 gld_lds per wave
#pragma unroll
    for (int c = 0; c < 2; ++c) {
      const int row = c * 32 + w * 8 + (l >> 3);
      const int g = l & 7;
      const int off = (g ^ (row & 7)) * 8;
      gld_lds16(Kb + (size_t)(t * 64 + row) * 64 + off, &Ks[buf][(c * 32 + w * 8) * 64]);
      gld_lds16(Vb + (size_t)row * 1024 + t * 64 + off, &VTs[buf][(c * 32 + w * 8) * 64]);
    }
  };

  // Q fragments (B operand): lane holds Q[q=lane&31][d = s4*16 + hi*8 + e]
  bf16x8 qf[4];
  {
    const unsigned short* qp =
        Q + (size_t)bh * 65536 + (size_t)(q0 + w * 32 + l31) * 64 + hi * 8;
#pragma unroll
    for (int s4 = 0; s4 < 4; ++s4) qf[s4] = *(const bf16x8*)(qp + s4 * 16);
  }

  // ---- rw bias acc via identity-fragment MFMA (once):
  // rwacc[r](q) = relw_t[crow(r,hi)][q]; used as C-input of each tile's first
  // QK^T MFMA -> per-tile rel_w bias costs ZERO VALU.
  f32x16 rwacc;
  bf16x8 onesA;
  {
    bf16x8 idA0, idA1, rwB0, rwB1;
    const short onebf = (short)0x3F80;
#pragma unroll
    for (int e = 0; e < 8; ++e) {
      idA0[e] = (l31 == hi * 8 + e) ? onebf : (short)0;
      idA1[e] = (l31 == 16 + hi * 8 + e) ? onebf : (short)0;
      onesA[e] = onebf;
      rwB0[e] = (short)relw_t[(size_t)bh * 32768 + (size_t)(hi * 8 + e) * 1024 +
                              q0 + w * 32 + l31];
      rwB1[e] = (short)relw_t[(size_t)bh * 32768 + (size_t)(16 + hi * 8 + e) * 1024 +
                              q0 + w * 32 + l31];
    }
    f32x16 z = {};
    rwacc = MFMA32(idA0, rwB0, z);
    rwacc = MFMA32(idA1, rwB1, rwacc);
  }

  f32x16 od0 = {}, od1 = {}, sumacc = {};
  int cur = 0;

  stage(0, 0);  // 4 KV loads in flight (+2 rhsL older)

  for (int t = 0; t < 16; ++t) {
    if (t < 15) {
      stage(cur ^ 1, t + 1);  // +4 -> 8 KV outstanding
      // retire tile t's 4 loads (and, at t=0, the rhsL loads which are older);
      // tile t+1's 4 remain in flight across this whole compute phase.
      asm volatile("s_waitcnt vmcnt(4)" ::: "memory");
    } else {
      asm volatile("s_waitcnt vmcnt(0)" ::: "memory");  // tail
    }
    __builtin_amdgcn_s_barrier();   // block-wide: tile t + rhsL visible
    __builtin_amdgcn_sched_barrier(0);

    // ---- S^T = K Q^T + rw-bias : D[k][q], lane: q = lane&31, k = crow(r,hi)
    f32x16 s0, s1;
    __builtin_amdgcn_s_setprio(1);
    {
      const int row0 = l31, row1 = 32 + l31;
      bf16x8 kf0 = *(const bf16x8*)&Ks[cur][row0 * 64 + ((hi ^ (row0 & 7)) * 8)];
      bf16x8 kf1 = *(const bf16x8*)&Ks[cur][row1 * 64 + ((hi ^ (row1 & 7)) * 8)];
      s0 = MFMA32(kf0, qf[0], rwacc);
      s1 = MFMA32(kf1, qf[0], rwacc);
    }
#pragma unroll
    for (int s4 = 1; s4 < 4; ++s4) {
      {
        const int row = l31;
        bf16x8 kf = *(const bf16x8*)&Ks[cur][row * 64 + (((s4 * 2 + hi) ^ (row & 7)) * 8)];
        s0 = MFMA32(kf, qf[s4], s0);
      }
      {
        const int row = 32 + l31;
        bf16x8 kf = *(const bf16x8*)&Ks[cur][row * 64 + (((s4 * 2 + hi) ^ (row & 7)) * 8)];
        s1 = MFMA32(kf, qf[s4], s1);
      }
    }
    __builtin_amdgcn_s_setprio(0);

    // ---- P = exp2(S + rh) directly (no max-sub; logits bounded), rh per half
    const float rh0 = bf2f(rhsL[(2 * t) * 128 + w * 32 + l31]);
    const float rh1 = bf2f(rhsL[(2 * t + 1) * 128 + w * 32 + l31]);
#pragma unroll
    for (int r = 0; r < 16; ++r) {
      s0[r] = exp2_raw(s0[r] + rh0);
      s1[r] = exp2_raw(s1[r] + rh1);
    }

    // ---- P -> bf16 B-operand fragments via cvt_pk + permlane32_swap (T12)
    bf16x8 pa[4];
#pragma unroll
    for (int ks = 0; ks < 4; ++ks) {
      unsigned int c0, c1, c2, c3;
      if (ks == 0) {
        c0 = cvt_pk_bf16(s0[0], s0[1]);  c1 = cvt_pk_bf16(s0[2], s0[3]);
        c2 = cvt_pk_bf16(s0[4], s0[5]);  c3 = cvt_pk_bf16(s0[6], s0[7]);
      } else if (ks == 1) {
        c0 = cvt_pk_bf16(s0[8], s0[9]);  c1 = cvt_pk_bf16(s0[10], s0[11]);
        c2 = cvt_pk_bf16(s0[12], s0[13]); c3 = cvt_pk_bf16(s0[14], s0[15]);
      } else if (ks == 2) {
        c0 = cvt_pk_bf16(s1[0], s1[1]);  c1 = cvt_pk_bf16(s1[2], s1[3]);
        c2 = cvt_pk_bf16(s1[4], s1[5]);  c3 = cvt_pk_bf16(s1[6], s1[7]);
      } else {
        c0 = cvt_pk_bf16(s1[8], s1[9]);  c1 = cvt_pk_bf16(s1[10], s1[11]);
        c2 = cvt_pk_bf16(s1[12], s1[13]); c3 = cvt_pk_bf16(s1[14], s1[15]);
      }
      uint2v x = __builtin_amdgcn_permlane32_swap(c0, c2, false, false);
      uint2v z = __builtin_amdgcn_permlane32_swap(c1, c3, false, false);
      union { unsigned int u[4]; bf16x8 v; } uu;
      uu.u[0] = x.x; uu.u[1] = z.x; uu.u[2] = x.y; uu.u[3] = z.y;
      pa[ks] = uu.v;
    }

    // ---- O += V^T P^T and row-sums += ones x P (sum on the MFMA pipe)
    __builtin_amdgcn_s_setprio(1);
#pragma unroll
    for (int ks = 0; ks < 4; ++ks) {
      {
        const int row = l31;
        bf16x8 vf = *(const bf16x8*)&VTs[cur][row * 64 + (((ks * 2 + hi) ^ (row & 7)) * 8)];
        od0 = MFMA32(vf, pa[ks], od0);
      }
      {
        const int row = 32 + l31;
        bf16x8 vf = *(const bf16x8*)&VTs[cur][row * 64 + (((ks * 2 + hi) ^ (row & 7)) * 8)];
        od1 = MFMA32(vf, pa[ks], od1);
      }
      sumacc = MFMA32(onesA, pa[ks], sumacc);
    }
    __builtin_amdgcn_s_setprio(0);

    // own ds_reads of buf[cur] consumed; barrier releases it for restaging
    asm volatile("s_waitcnt lgkmcnt(0)" ::: "memory");
    __builtin_amdgcn_sched_barrier(0);
    __builtin_amdgcn_s_barrier();
    cur ^= 1;
  }

  // ---- epilogue: every sumacc row = full row-sum for q = lane&31
  const float inv = 1.f / sumacc[0];
  const int b = bh / 12, h = bh % 12;
  const int n = q0 + w * 32 + l31;
  unsigned short* ob = out + ((size_t)(b * 1024 + n)) * 768 + h * 64;
#pragma unroll
  for (int r4 = 0; r4 < 4; ++r4) {
    ushort4 p0, p1;
    p0.x = f2bf(od0[r4 * 4 + 0] * inv); p0.y = f2bf(od0[r4 * 4 + 1] * inv);
    p0.z = f2bf(od0[r4 * 4 + 2] * inv); p0.w = f2bf(od0[r4 * 4 + 3] * inv);
    p1.x = f2bf(od1[r4 * 4 + 0] * inv); p1.y = f2bf(od1[r4 * 4 + 1] * inv);
    p1.z = f2bf(od1[r4 * 4 + 2] * inv); p1.w = f2bf(od1[r4 * 4 + 3] * inv);
    *(ushort4*)(ob + 8 * r4 + 4 * hi) = p0;
    *(ushort4*)(ob + 32 + 8 * r4 + 4 * hi) = p1;
  }
}

// ---------------------------------------------------------------- launch
extern "C" void kernel_launch(void* const* d_in, const int* in_sizes, int n_in,
                              void* d_out, int out_size, void* d_ws, size_t ws_size,
                              hipStream_t stream) {
  const float* x      = (const float*)d_in[0];
  const float* qkv_w  = (const float*)d_in[1];
  const float* rph    = (const float*)d_in[2];
  const float* rpw    = (const float*)d_in[3];
  const float* proj_w = (const float*)d_in[4];
  const float* proj_b = (const float*)d_in[5];
  float* out = (float*)d_out;

  char* ws = (char*)d_ws;
  unsigned short* xb     = (unsigned short*)(ws);              // 12,582,912 B (reused as attn_out)
  unsigned short* wqkv   = (unsigned short*)(ws + 12582912);   //  3,538,944 B
  unsigned short* wproj  = (unsigned short*)(ws + 16121856);   //  1,179,648 B
  unsigned short* qb     = (unsigned short*)(ws + 17301504);   // 12,582,912 B
  unsigned short* kb     = (unsigned short*)(ws + 29884416);   // 12,582,912 B
  unsigned short* vbT    = (unsigned short*)(ws + 42467328);   // 12,582,912 B
  unsigned short* relh_t = (unsigned short*)(ws + 55050240);   //  6,291,456 B
  unsigned short* relw_t = (unsigned short*)(ws + 61341696);   //  6,291,456 B (end 67,633,152)

  convert3_kernel<<<8448, 256, 0, stream>>>(x, qkv_w, proj_w, xb, wqkv, wproj);

  gemm_nt<0><<<dim3(64, 18), 256, 0, stream>>>(xb, wqkv, qb, kb, vbT, nullptr, nullptr);

  rel_kernel<<<dim3(8, 96), 256, 0, stream>>>(qb, rph, rpw, relh_t, relw_t);

  attn_kernel<<<768, 256, 0, stream>>>(qb, kb, vbT, relh_t, relw_t, xb);

  gemm_nt<1><<<dim3(64, 6), 256, 0, stream>>>(xb, wproj, nullptr, nullptr, nullptr, out, proj_b);
}